// Round 9
// baseline (228.573 us; speedup 1.0000x reference)
//
#include <hip/hip_runtime.h>
#include <hip/hip_bf16.h>

// MHA: N=2, S=2048, E=1024, H=16, Dh=64. fp32 in/out, internal bf16 MFMA.
// R10-R15: attn at 40.8 us (~845 TF plateau): swapped QK^T 32x32,
// in-register P (cvt_pk+permlane32_swap), dbuf K/V, setprio, lds_barrier.
// R16: fused q/k/v proj reading fp32 d_in directly (kills the 90 MB
// activation-cast pass). PASSED but proj was latency-broken at 71 us:
// reg-staged A with depth-1 prefetch issued after __syncthreads ->
// ~900-cyc HBM latency exposed every K-step (MfmaUtil 13.5, VALU 11,
// HBM 11% - all idle).
// R17: A staged AS FP32 via gl_lds16 (async queue = latency-tolerant,
// same structure as the proven qk_gemm); bf16 conversion moved to
// fragment-read time (2x ds_read_b128 fp32 + 4x v_cvt_pk_bf16_f32 per
// frag). +16 cvt_pk/wave/K-step on an 11%-busy VALU. Read pattern is
// uniform 8 lanes/4-bank group = b128 floor -> 0 conflicts.

typedef short bf16x8 __attribute__((ext_vector_type(8)));
typedef short bf16x4 __attribute__((ext_vector_type(4)));
typedef float f32x4 __attribute__((ext_vector_type(4)));
typedef float f32x16 __attribute__((ext_vector_type(16)));
typedef unsigned u32x2 __attribute__((ext_vector_type(2)));
typedef unsigned u32x4 __attribute__((ext_vector_type(4)));

constexpr int S = 2048;
constexpr int E = 1024;
constexpr int H = 16;
constexpr int D = 64;
constexpr int M = 2 * S;  // 4096 rows total
// 1/sqrt(Dh) * log2(e): q is pre-scaled so QK^T scores are exp2-domain.
#define QSCALE 0.18033688011112042f

static __device__ __forceinline__ short f2bf_rne(float x) {
  unsigned u = __builtin_bit_cast(unsigned, x);
  u += 0x7fff + ((u >> 16) & 1);  // RNE, finite inputs only
  return (short)(u >> 16);
}
static __device__ __forceinline__ bf16x8 cvt8(float4 a, float4 b) {
  bf16x8 t;
  t[0] = f2bf_rne(a.x); t[1] = f2bf_rne(a.y);
  t[2] = f2bf_rne(a.z); t[3] = f2bf_rne(a.w);
  t[4] = f2bf_rne(b.x); t[5] = f2bf_rne(b.y);
  t[6] = f2bf_rne(b.z); t[7] = f2bf_rne(b.w);
  return t;
}
static __device__ __forceinline__ float fast_exp2(float x) {
#if __has_builtin(__builtin_amdgcn_exp2f)
  return __builtin_amdgcn_exp2f(x);
#else
  return __expf(0.69314718055994531f * x);
#endif
}
// 2 f32 -> u32 of 2 bf16 (lo = a). RNE, matches f2bf_rne.
static __device__ __forceinline__ unsigned cvtpk(float a, float b) {
  unsigned r;
  asm("v_cvt_pk_bf16_f32 %0, %1, %2" : "=v"(r) : "v"(a), "v"(b));
  return r;
}
// a[32..63] <-> b[0..31]. After: a = {a_lo, b_lo}, b = {a_hi, b_hi}.
static __device__ __forceinline__ void plswap(unsigned& a, unsigned& b) {
#if __has_builtin(__builtin_amdgcn_permlane32_swap)
  u32x2 t = __builtin_amdgcn_permlane32_swap(a, b, false, false);
  a = t[0]; b = t[1];
#else
  asm("v_permlane32_swap_b32 %0, %1" : "+v"(a), "+v"(b));
#endif
}
// LDS-visibility barrier that does NOT drain vmcnt.
static __device__ __forceinline__ void lds_barrier() {
  asm volatile("s_waitcnt lgkmcnt(0)" ::: "memory");
  __builtin_amdgcn_s_barrier();
}

// Async global->LDS, 16 B per lane. lds base must be wave-uniform; lane i's
// 16 B lands at lds + i*16. Global address is per-lane.
static __device__ __forceinline__ void gl_lds16(const short* g, short* l) {
  __builtin_amdgcn_global_load_lds(
      (const __attribute__((address_space(1))) void*)g,
      (__attribute__((address_space(3))) void*)l, 16, 0, 0);
}
static __device__ __forceinline__ void gl_lds16f(const float* g, float* l) {
  __builtin_amdgcn_global_load_lds(
      (const __attribute__((address_space(1))) void*)g,
      (__attribute__((address_space(3))) void*)l, 16, 0, 0);
}

// ---------------------------------------------------------------------------
// XOR-swizzled tile layouts.
// bf16 [rows x 32] (64 B/row): pairs of rows = 128 B = 8 chunks of 16 B;
//   chunk l of pair p lives at k = l ^ (p&7).
// fp32 [rows x 32] (128 B/row): each ROW = 8 chunks of 16 B (4 fp32);
//   chunk l of row r lives at k = l ^ (r&7). Stage: lane i of segment s
//   (1 KB = 8 rows) covers row s*8+(i>>3), k=i&7 -> global col
//   (k^(row&7))*4. Read cols 8q..8q+7 of row r: k0=(2q)^(r&7), k1=k0^1.
// ---------------------------------------------------------------------------

// ---------------------------------------------------------------------------
// cast_w: 4 weight matrices fp32 -> bf16. grid (512, 4).
// ---------------------------------------------------------------------------
__global__ __launch_bounds__(256) void cast_w(
    const float* __restrict__ wq, const float* __restrict__ wk,
    const float* __restrict__ wv, const float* __restrict__ wo,
    short* __restrict__ wqb, short* __restrict__ wkb,
    short* __restrict__ wvb, short* __restrict__ wob) {
  const float* s;
  short* d;
  switch (blockIdx.y) {
    case 0: s = wq; d = wqb; break;
    case 1: s = wk; d = wkb; break;
    case 2: s = wv; d = wvb; break;
    default: s = wo; d = wob; break;
  }
  size_t i = ((size_t)blockIdx.x * 256 + threadIdx.x) * 8;
  *(bf16x8*)&d[i] = cvt8(*(const float4*)&s[i], *(const float4*)&s[i + 4]);
}

// ---------------------------------------------------------------------------
// proj_gemm: fused q, k AND v projections, 128x128 tiles, 768 blocks
// (3 blocks/CU). A = ORIGINAL fp32 activations staged via gl_lds16 into a
// 16 KB fp32 LDS tile (async, latency-tolerant); bf16 conversion happens
// at frag-read (2x ds_read_b128 + 4x cvt_pk). B = pre-cast bf16 weights
// via gl_lds16. XCD swizzle: c=b&7, r=b>>3; bn=r&7; t=c*12+(r>>3);
// z=t>>5 (0=q,1=k,2=v); bm=t&31.
// Outputs: z=0 qb (exp2-scaled), z=1 kb, z=2 vtb [n,h,d,s] bf16 — all
// distinct buffers, zero aliasing with inputs.
// ---------------------------------------------------------------------------
__global__ __launch_bounds__(256) void proj_gemm(
    const float* __restrict__ qs, const float* __restrict__ ks,
    const float* __restrict__ vsrc, const short* __restrict__ wqb,
    const short* __restrict__ wkb, const short* __restrict__ wvb,
    const float* __restrict__ bq, const float* __restrict__ bk,
    const float* __restrict__ bv, short* __restrict__ qb,
    short* __restrict__ kb, short* __restrict__ vtb) {
  __shared__ __align__(16) float asf[128 * 32];   // fp32 A tile, 16 KB
  __shared__ __align__(16) short bs[128 * 32];    // bf16 B tile, 8 KB
  const int tid = threadIdx.x;
  const int lane = tid & 63, w = tid >> 6;
  const int l15 = lane & 15, quad = lane >> 4;
  const int wm = w & 1, wn = w >> 1;

  const int b = blockIdx.x;
  const int c = b & 7, r = b >> 3;
  const int bn = r & 7;
  const int t = c * 12 + (r >> 3);  // 0..95
  const int z = t >> 5, bm = t & 31;

  const float* A = z == 0 ? qs : (z == 1 ? ks : vsrc);
  const short* Bw = z == 0 ? wqb : (z == 1 ? wkb : wvb);
  const float* bias = z == 0 ? bq : (z == 1 ? bk : bv);

  // A: 4 fp32 segments per wave (16 total); B: 2 bf16 segments per wave.
  const float* afp[4];
  int aldsb[4];
#pragma unroll
  for (int cc = 0; cc < 4; ++cc) {
    int seg = w * 4 + cc;
    int row = seg * 8 + (lane >> 3);       // 0..127
    int kch = lane & 7;
    int l = kch ^ (row & 7);
    aldsb[cc] = seg * 256;                 // fp32 index (1 KB/segment)
    afp[cc] = &A[(size_t)(bm * 128 + row) * E + l * 4];
  }
  const short* bgp[2];
  int bldsb[2];
#pragma unroll
  for (int cc = 0; cc < 2; ++cc) {
    int seg = w * 2 + cc;
    int p = seg * 8 + (lane >> 3), kc = lane & 7;
    int l = kc ^ (p & 7);
    int row = 2 * p + (l >> 2), col = (l & 3) * 8;
    bldsb[cc] = seg * 512;
    bgp[cc] = &Bw[(size_t)(bn * 128 + row) * E + col];
  }

  f32x4 acc[4][4] = {};
  for (int k0 = 0; k0 < E; k0 += 32) {
    __syncthreads();  // prev frag reads done; LDS free
#pragma unroll
    for (int cc = 0; cc < 4; ++cc) gl_lds16f(afp[cc] + k0, &asf[aldsb[cc]]);
#pragma unroll
    for (int cc = 0; cc < 2; ++cc) gl_lds16(bgp[cc] + k0, &bs[bldsb[cc]]);
    __syncthreads();  // vmcnt drained by compiler -> tiles ready

    bf16x8 af[4], bf[4];
#pragma unroll
    for (int tt = 0; tt < 4; ++tt) {
      int ra = wm * 64 + tt * 16 + l15;
      int k0q = (2 * quad) ^ (ra & 7);
      float4 v0 = *(float4*)&asf[ra * 32 + k0q * 4];
      float4 v1 = *(float4*)&asf[ra * 32 + (k0q ^ 1) * 4];
      u32x4 pk;
      pk[0] = cvtpk(v0.x, v0.y); pk[1] = cvtpk(v0.z, v0.w);
      pk[2] = cvtpk(v1.x, v1.y); pk[3] = cvtpk(v1.z, v1.w);
      af[tt] = __builtin_bit_cast(bf16x8, pk);
      int rb = wn * 64 + tt * 16 + l15;
      int pb2 = rb >> 1, lb = (rb & 1) * 4 + quad, kb2 = lb ^ (pb2 & 7);
      bf[tt] = *(bf16x8*)&bs[pb2 * 64 + kb2 * 8];
    }
#pragma unroll
    for (int mt = 0; mt < 4; ++mt)
#pragma unroll
      for (int nt = 0; nt < 4; ++nt)
        acc[mt][nt] = __builtin_amdgcn_mfma_f32_16x16x32_bf16(
            af[mt], bf[nt], acc[mt][nt], 0, 0, 0);
  }

#pragma unroll
  for (int mt = 0; mt < 4; ++mt)
#pragma unroll
    for (int nt = 0; nt < 4; ++nt)
#pragma unroll
      for (int rr = 0; rr < 4; ++rr) {
        int row = bm * 128 + wm * 64 + mt * 16 + quad * 4 + rr;
        int col = bn * 128 + wn * 64 + nt * 16 + l15;
        float v = acc[mt][nt][rr] + bias[col];
        int n = row >> 11, s = row & 2047, h = col >> 6, d = col & 63;
        if (z == 0) {        // q, pre-scaled into exp2 domain
          qb[(((size_t)(n * H + h) * S) + s) * D + d] = f2bf_rne(v * QSCALE);
        } else if (z == 1) { // k
          kb[(((size_t)(n * H + h) * S) + s) * D + d] = f2bf_rne(v);
        } else {             // v -> transposed [n,h,d,s]
          vtb[(((size_t)(n * H + h) * D) + d) * S + s] = f2bf_rne(v);
        }
      }
}

// ---------------------------------------------------------------------------
// 64x128-tile GEMM core, 512 blocks, XCD swizzle: bn=r&7, bm=c*8+(r>>3).
// MODE 1: out projection -> fp32 row-major + bias (only mode used).
// ---------------------------------------------------------------------------
template <int MODE>
__global__ __launch_bounds__(256) void gemm64(const short* __restrict__ A,
                                              const short* __restrict__ Bw,
                                              const float* __restrict__ bias,
                                              void* __restrict__ outp) {
  __shared__ __align__(16) short as[64 * 32];
  __shared__ __align__(16) short bs[128 * 32];
  const int tid = threadIdx.x;
  const int lane = tid & 63, w = tid >> 6;
  const int l15 = lane & 15, quad = lane >> 4;
  const int wm = w & 1, wn = w >> 1;

  const int b = blockIdx.x;
  const int c = b & 7, r = b >> 3;
  const int bn = r & 7;
  const int bm = c * 8 + (r >> 3);  // 0..63

  const short* agp;
  int aldsb;
  {
    int seg = w;
    int p = seg * 8 + (lane >> 3), kc = lane & 7;
    int l = kc ^ (p & 7);
    int row = 2 * p + (l >> 2), col = (l & 3) * 8;
    aldsb = seg * 512;
    agp = &A[(size_t)(bm * 64 + row) * E + col];
  }
  const short* bgp[2];
  int bldsb[2];
#pragma unroll
  for (int cc = 0; cc < 2; ++cc) {
    int seg = w * 2 + cc;
    int p = seg * 8 + (lane >> 3), kc = lane & 7;
    int l = kc ^ (p & 7);
    int row = 2 * p + (l >> 2), col = (l & 3) * 8;
    bldsb[cc] = seg * 512;
    bgp[cc] = &Bw[(size_t)(bn * 128 + row) * E + col];
  }

  f32x4 acc[2][4] = {};
  for (int k0 = 0; k0 < E; k0 += 32) {
    __syncthreads();
    gl_lds16(agp + k0, &as[aldsb]);
#pragma unroll
    for (int cc = 0; cc < 2; ++cc) gl_lds16(bgp[cc] + k0, &bs[bldsb[cc]]);
    __syncthreads();

    bf16x8 af[2], bf[4];
#pragma unroll
    for (int tt = 0; tt < 2; ++tt) {
      int ra = wm * 32 + tt * 16 + l15;
      int pa2 = ra >> 1, la = (ra & 1) * 4 + quad, ka = la ^ (pa2 & 7);
      af[tt] = *(bf16x8*)&as[pa2 * 64 + ka * 8];
    }
#pragma unroll
    for (int tt = 0; tt < 4; ++tt) {
      int rb = wn * 64 + tt * 16 + l15;
      int pb2 = rb >> 1, lb = (rb & 1) * 4 + quad, kb2 = lb ^ (pb2 & 7);
      bf[tt] = *(bf16x8*)&bs[pb2 * 64 + kb2 * 8];
    }
#pragma unroll
    for (int mt = 0; mt < 2; ++mt)
#pragma unroll
      for (int nt = 0; nt < 4; ++nt)
        acc[mt][nt] = __builtin_amdgcn_mfma_f32_16x16x32_bf16(
            af[mt], bf[nt], acc[mt][nt], 0, 0, 0);
  }

#pragma unroll
  for (int mt = 0; mt < 2; ++mt)
#pragma unroll
    for (int nt = 0; nt < 4; ++nt)
#pragma unroll
      for (int rr = 0; rr < 4; ++rr) {
        int row = bm * 64 + wm * 32 + mt * 16 + quad * 4 + rr;
        int col = bn * 128 + wn * 64 + nt * 16 + l15;
        float v = acc[mt][nt][rr] + bias[col];
        if (MODE == 0) {
          int n = row >> 11, s = row & 2047, h = col >> 6, d = col & 63;
          ((short*)outp)[(((size_t)(n * H + h) * D) + d) * S + s] =
              f2bf_rne(v);
        } else {
          ((float*)outp)[(size_t)row * E + col] = v;
        }
      }
}

// ---------------------------------------------------------------------------
// Flash attention (R15 form, unchanged): 8 waves x 32 q-rows, grid (8,32),
// XCD-pinned heads, swapped QK^T on mfma_32x32x16, in-register P via
// cvt_pk+permlane32_swap, dbuf K/V, setprio on MFMA, lds_barrier per tile.
// ---------------------------------------------------------------------------
__global__ __launch_bounds__(512) void attn_kernel(const short* __restrict__ q,
                                                   const short* __restrict__ k,
                                                   const short* __restrict__ vt,
                                                   short* __restrict__ ctx) {
  __shared__ __align__(16) short ksb[2][128 * 72];  // 128 keys x 64 d
  __shared__ __align__(16) short vsb[2][64 * 136];  // 64 d x 128 keys (V^T)

  const int tid = threadIdx.x;
  const int lane = tid & 63, wv = tid >> 6;  // 8 waves
  const int l31 = lane & 31, h = lane >> 5;

  const int bid = blockIdx.y * gridDim.x + blockIdx.x;  // 0..255
  const int c = bid & 7, r = bid >> 3;
  const int qt = r & 7;             // 8 q-tiles of 256 rows
  const int hz = c * 4 + (r >> 3);  // 0..31, 4 heads per XCD
  const int hh = hz & 15, nn = hz >> 4;

  const size_t base = (size_t)(nn * H + hh) * S * D;
  const int q0 = qt * 256 + wv * 32;

  bf16x8 qf[4];
#pragma unroll
  for (int kd = 0; kd < 4; ++kd)
    qf[kd] = *(const bf16x8*)&q[base + (size_t)(q0 + l31) * D + kd * 16 + h * 8];

  f32x16 o[2] = {};   // O[q=crow(r,h)][d=dc*32+l31]
  float lsum = 0.f;

  bf16x8 pk[2], pv[2];
  auto loadKV = [&](int j0) {
#pragma unroll
    for (int cc = 0; cc < 2; ++cc) {
      int ch = cc * 512 + tid;
      int kr = ch >> 3, kc = (ch & 7) * 8;   // 128 x 64
      pk[cc] = *(const bf16x8*)&k[base + (size_t)(j0 + kr) * D + kc];
      int vr = ch >> 4, vc = (ch & 15) * 8;  // 64 x 128
      pv[cc] = *(const bf16x8*)&vt[base + (size_t)vr * S + j0 + vc];
    }
  };
  auto storeKV = [&](int bufi) {
#pragma unroll
    for (int cc = 0; cc < 2; ++cc) {
      int ch = cc * 512 + tid;
      int kr = ch >> 3, kc = (ch & 7) * 8;
      *(bf16x8*)&ksb[bufi][kr * 72 + kc] = pk[cc];
      int vr = ch >> 4, vc = (ch & 15) * 8;
      *(bf16x8*)&vsb[bufi][vr * 136 + vc] = pv[cc];
    }
  };

  loadKV(0);
  storeKV(0);
  loadKV(128);
  lds_barrier();  // buf0 visible; tile-1 loads stay in flight

  for (int t = 0; t < 16; ++t) {
    const int cur = t & 1;
    if (t + 1 < 16) storeKV(cur ^ 1);      // tile t+1 (regs from last iter)
    if (t + 2 < 16) loadKV((t + 2) * 128); // prefetch tile t+2
    const short* ks = ksb[cur];
    const short* vs = vsb[cur];

#pragma unroll
    for (int half = 0; half < 2; ++half) {
      // QK^T: sc[c2] over keys half*64 + c2*32 + crow(r,h), q = l31.
      f32x16 sc[2] = {};
      __builtin_amdgcn_s_setprio(1);
#pragma unroll
      for (int c2 = 0; c2 < 2; ++c2)
#pragma unroll
        for (int kd = 0; kd < 4; ++kd) {
          bf16x8 kf = *(bf16x8*)&ks[(half * 64 + c2 * 32 + l31) * 72 +
                                    kd * 16 + h * 8];
          sc[c2] = __builtin_amdgcn_mfma_f32_32x32x16_bf16(kf, qf[kd], sc[c2],
                                                           0, 0, 0);
        }
      __builtin_amdgcn_s_setprio(0);

      // Softmax (fixed-base exp2) + in-register P->bf16 repack.
      bf16x8 pa[4];
#pragma unroll
      for (int c2 = 0; c2 < 2; ++c2) {
        float pe[16];
#pragma unroll
        for (int rr = 0; rr < 16; ++rr) {
          float p = fast_exp2(sc[c2][rr]);
          lsum += p;
          pe[rr] = p;
        }
#pragma unroll
        for (int kk = 0; kk < 2; ++kk) {
          unsigned A0 = cvtpk(pe[8 * kk + 0], pe[8 * kk + 1]);
          unsigned A1 = cvtpk(pe[8 * kk + 2], pe[8 * kk + 3]);
          unsigned B0 = cvtpk(pe[8 * kk + 4], pe[8 * kk + 5]);
          unsigned B1 = cvtpk(pe[8 * kk + 6], pe[8 * kk + 7]);
          plswap(A0, B0);
          plswap(A1, B1);
          u32x4 tt;
          tt[0] = A0; tt[1] = A1; tt[2] = B0; tt[3] = B1;
          pa[c2 * 2 + kk] = __builtin_bit_cast(bf16x8, tt);
        }
      }

      // PV: O[q][d] += P x V. B-frag: V[key=ks2*16+h*8..+7][d=dc*32+l31].
      __builtin_amdgcn_s_setprio(1);
#pragma unroll
      for (int ks2 = 0; ks2 < 4; ++ks2)
#pragma unroll
        for (int dc = 0; dc < 2; ++dc) {
          bf16x8 vf = *(bf16x8*)&vs[(dc * 32 + l31) * 136 + half * 64 +
                                    ks2 * 16 + h * 8];
          o[dc] = __builtin_amdgcn_mfma_f32_32x32x16_bf16(pa[ks2], vf, o[dc],
                                                          0, 0, 0);
        }
      __builtin_amdgcn_s_setprio(0);
    }
    lds_barrier();
  }

  // lane (l31,h) holds partial denom for q=l31 over its h-half keys.
  lsum += __shfl_xor(lsum, 32);
  float invq = 1.0f / lsum;  // denom for q = l31

#pragma unroll
  for (int rr = 0; rr < 16; ++rr) {
    int crow = (rr & 3) + 8 * (rr >> 2) + 4 * h;   // q-row of this reg
    float inv = __shfl(invq, crow);                // lane crow owns that q
    int row = q0 + crow;
#pragma unroll
    for (int dc = 0; dc < 2; ++dc) {
      ctx[((size_t)(nn * S + row)) * E + hh * D + dc * 32 + l31] =
          f2bf_rne(o[dc][rr] * inv);
    }
  }
}

// ---------------------------------------------------------------------------
extern "C" void kernel_launch(void* const* d_in, const int* in_sizes, int n_in,
                              void* d_out, int out_size, void* d_ws,
                              size_t ws_size, hipStream_t stream) {
  const float* values  = (const float*)d_in[0];
  const float* keys    = (const float*)d_in[1];
  const float* queries = (const float*)d_in[2];
  const float* b_v = (const float*)d_in[4];
  const float* b_k = (const float*)d_in[6];
  const float* b_q = (const float*)d_in[8];
  const float* W_v = (const float*)d_in[3];
  const float* W_k = (const float*)d_in[5];
  const float* W_q = (const float*)d_in[7];
  const float* W_o = (const float*)d_in[9];
  const float* b_o = (const float*)d_in[10];

  const size_t X = (size_t)M * E;      // 4M elements (8 MB bf16)
  const size_t W = (size_t)E * E;      // 1M elements (2 MB bf16)

  // d_out (16 MB): qb [0..X) + kb [X..2X); both dead after attn, before
  // gemm64<1> overwrites d_out with fp32.
  short* qb = (short*)d_out;
  short* kb = (short*)d_out + X;
  // d_ws (32 MB): vtb, ctx, 4 bf16 weights (24 MB used).
  short* vtb = (short*)d_ws;           // [0 .. X)
  short* ctx = vtb + X;                // [X .. 2X)
  short* wqb = ctx + X;                // [2X ..)
  short* wkb = wqb + W;
  short* wvb = wkb + W;
  short* wob = wvb + W;

  cast_w<<<dim3(512, 4), 256, 0, stream>>>(W_q, W_k, W_v, W_o,
                                           wqb, wkb, wvb, wob);
  proj_gemm<<<768, 256, 0, stream>>>(queries, keys, values, wqb, wkb, wvb,
                                     b_q, b_k, b_v, qb, kb, vtb);
  attn_kernel<<<dim3(8, 32), 512, 0, stream>>>(qb, kb, vtb, ctx);
  gemm64<1><<<512, 256, 0, stream>>>(ctx, wob, b_o, d_out);
}

// Round 10
// 206.402 us; speedup vs baseline: 1.1074x; 1.1074x over previous
//
#include <hip/hip_runtime.h>
#include <hip/hip_bf16.h>

// MHA: N=2, S=2048, E=1024, H=16, Dh=64. fp32 in/out, internal bf16 MFMA.
// R10-R15: attn at 40.8 us (~845 TF plateau): swapped QK^T 32x32,
// in-register P (cvt_pk+permlane32_swap), dbuf K/V, setprio, lds_barrier.
// R16/R17 (ABANDONED): fused fp32-direct projections. Post-mortem: per
// XCD the fused kernel needs 12 fp32 A-panels (6 MB) + 3 weights (6 MB)
// vs 4 MB L2 -> thrash -> latency-bound at 71-83 us. The split qk_gemm
// fits L2 exactly (8 bf16 panels 2 MB + 1 weight 2 MB = 4 MB).
// R18: R15 structure (best measured, 210.07) + BK 32->64 in all GEMMs:
// 16 barrier-pairs per kernel instead of 32, same staged bytes, same
// bank profile (single-row XOR swizzle k = l ^ (row&7), 8 lanes per
// 16 B chunk position on frag reads). LDS qk 32 KB / gemm64 24 KB ->
// still 2 blocks/CU. attn + cast_all untouched.

typedef short bf16x8 __attribute__((ext_vector_type(8)));
typedef short bf16x4 __attribute__((ext_vector_type(4)));
typedef float f32x4 __attribute__((ext_vector_type(4)));
typedef float f32x16 __attribute__((ext_vector_type(16)));
typedef unsigned u32x2 __attribute__((ext_vector_type(2)));
typedef unsigned u32x4 __attribute__((ext_vector_type(4)));

constexpr int S = 2048;
constexpr int E = 1024;
constexpr int H = 16;
constexpr int D = 64;
constexpr int M = 2 * S;  // 4096 rows total
// 1/sqrt(Dh) * log2(e): q is pre-scaled so QK^T scores are exp2-domain.
#define QSCALE 0.18033688011112042f

static __device__ __forceinline__ short f2bf_rne(float x) {
  unsigned u = __builtin_bit_cast(unsigned, x);
  u += 0x7fff + ((u >> 16) & 1);  // RNE, finite inputs only
  return (short)(u >> 16);
}
static __device__ __forceinline__ bf16x8 cvt8(float4 a, float4 b) {
  bf16x8 t;
  t[0] = f2bf_rne(a.x); t[1] = f2bf_rne(a.y);
  t[2] = f2bf_rne(a.z); t[3] = f2bf_rne(a.w);
  t[4] = f2bf_rne(b.x); t[5] = f2bf_rne(b.y);
  t[6] = f2bf_rne(b.z); t[7] = f2bf_rne(b.w);
  return t;
}
static __device__ __forceinline__ float fast_exp2(float x) {
#if __has_builtin(__builtin_amdgcn_exp2f)
  return __builtin_amdgcn_exp2f(x);
#else
  return __expf(0.69314718055994531f * x);
#endif
}
// 2 f32 -> u32 of 2 bf16 (lo = a). RNE, matches f2bf_rne.
static __device__ __forceinline__ unsigned cvtpk(float a, float b) {
  unsigned r;
  asm("v_cvt_pk_bf16_f32 %0, %1, %2" : "=v"(r) : "v"(a), "v"(b));
  return r;
}
// a[32..63] <-> b[0..31]. After: a = {a_lo, b_lo}, b = {a_hi, b_hi}.
static __device__ __forceinline__ void plswap(unsigned& a, unsigned& b) {
#if __has_builtin(__builtin_amdgcn_permlane32_swap)
  u32x2 t = __builtin_amdgcn_permlane32_swap(a, b, false, false);
  a = t[0]; b = t[1];
#else
  asm("v_permlane32_swap_b32 %0, %1" : "+v"(a), "+v"(b));
#endif
}
// LDS-visibility barrier that does NOT drain vmcnt.
static __device__ __forceinline__ void lds_barrier() {
  asm volatile("s_waitcnt lgkmcnt(0)" ::: "memory");
  __builtin_amdgcn_s_barrier();
}

// Async global->LDS, 16 B per lane. lds base must be wave-uniform; lane i's
// 16 B lands at lds + i*16. Global address is per-lane.
static __device__ __forceinline__ void gl_lds16(const short* g, short* l) {
  __builtin_amdgcn_global_load_lds(
      (const __attribute__((address_space(1))) void*)g,
      (__attribute__((address_space(3))) void*)l, 16, 0, 0);
}

// ---------------------------------------------------------------------------
// BK=64 XOR-swizzled tile layout for [rows x 64] bf16 tiles (128 B/row).
// Each row = 8 chunks of 16 B; logical chunk l of row r lives at physical
// chunk k = l ^ (r&7). Staging segment s (1 KB = 8 rows), lane i: row =
// s*8 + (i>>3), k = i&7, l = k ^ (row&7) -> global cols l*8..l*8+7.
// Read (row r, logical chunk lq): shortOff = r*64 + (lq^(r&7))*8.
// Frag read conflict profile: 8 lanes per 16 B chunk position (same as
// the old pair-swizzle) -> b128 floor, ~0 conflicts.
// ---------------------------------------------------------------------------

// ---------------------------------------------------------------------------
// cast_all: q->qbf, k->kbf, v->vbf, 4 weights -> bf16. grid (2048, 7).
// ---------------------------------------------------------------------------
__global__ __launch_bounds__(256) void cast_all(
    const float* __restrict__ qs, const float* __restrict__ ks,
    const float* __restrict__ vsrc, const float* __restrict__ wq,
    const float* __restrict__ wk, const float* __restrict__ wv,
    const float* __restrict__ wo, short* __restrict__ qbf,
    short* __restrict__ kbf, short* __restrict__ vbf, short* __restrict__ wqb,
    short* __restrict__ wkb, short* __restrict__ wvb, short* __restrict__ wob) {
  const float* s;
  short* d;
  switch (blockIdx.y) {
    case 0: s = qs; d = qbf; break;
    case 1: s = ks; d = kbf; break;
    case 2: s = vsrc; d = vbf; break;
    case 3: if (blockIdx.x >= 512) return; s = wq; d = wqb; break;
    case 4: if (blockIdx.x >= 512) return; s = wk; d = wkb; break;
    case 5: if (blockIdx.x >= 512) return; s = wv; d = wvb; break;
    default: if (blockIdx.x >= 512) return; s = wo; d = wob; break;
  }
  size_t i = ((size_t)blockIdx.x * 256 + threadIdx.x) * 8;
  *(bf16x8*)&d[i] = cvt8(*(const float4*)&s[i], *(const float4*)&s[i + 4]);
}

// ---------------------------------------------------------------------------
// qk_gemm: fused q & k projections, 128x128 tiles, BK=64, 512 blocks.
// XCD swizzle: c=b&7, r=b>>3; bn=r&7; t=c*8+(r>>3); z=t>>5; bm=t&31.
// Per XCD: 8 bf16 A-panels (2 MB) + 1 weight (2 MB) = 4 MB = L2 fit.
// ---------------------------------------------------------------------------
__global__ __launch_bounds__(256) void qk_gemm(
    const short* __restrict__ qbf, const short* __restrict__ kbf,
    const short* __restrict__ wqb, const short* __restrict__ wkb,
    const float* __restrict__ bq, const float* __restrict__ bk,
    short* __restrict__ qb, short* __restrict__ kb) {
  __shared__ __align__(16) short as[128 * 64];  // 16 KB
  __shared__ __align__(16) short bs[128 * 64];  // 16 KB
  const int tid = threadIdx.x;
  const int lane = tid & 63, w = tid >> 6;
  const int l15 = lane & 15, quad = lane >> 4;
  const int wm = w & 1, wn = w >> 1;

  const int b = blockIdx.x;
  const int c = b & 7, r = b >> 3;
  const int bn = r & 7;
  const int t = c * 8 + (r >> 3);
  const int z = t >> 5, bm = t & 31;

  const short* A = z ? kbf : qbf;
  const short* Bw = z ? wkb : wqb;
  const float* bias = z ? bk : bq;

  // staging: 4 segments per wave for each of A and B (16 KB tiles each)
  const short* agp[4];
  const short* bgp[4];
  int ldsb[4];
#pragma unroll
  for (int cc = 0; cc < 4; ++cc) {
    int seg = w * 4 + cc;
    int row = seg * 8 + (lane >> 3), kc = lane & 7;
    int l = kc ^ (row & 7);
    int col = l * 8;
    ldsb[cc] = seg * 512;
    agp[cc] = &A[(size_t)(bm * 128 + row) * E + col];
    bgp[cc] = &Bw[(size_t)(bn * 128 + row) * E + col];
  }

  f32x4 acc[4][4] = {};
  for (int k0 = 0; k0 < E; k0 += 64) {
    __syncthreads();  // prev frag reads done; LDS free
#pragma unroll
    for (int cc = 0; cc < 4; ++cc) {
      gl_lds16(agp[cc] + k0, &as[ldsb[cc]]);
      gl_lds16(bgp[cc] + k0, &bs[ldsb[cc]]);
    }
    __syncthreads();  // vmcnt drained by compiler before barrier -> tile ready

#pragma unroll
    for (int kk = 0; kk < 2; ++kk) {
      bf16x8 af[4], bf[4];
#pragma unroll
      for (int tt = 0; tt < 4; ++tt) {
        int ra = wm * 64 + tt * 16 + l15;
        int ka = (kk * 4 + quad) ^ (ra & 7);
        af[tt] = *(bf16x8*)&as[ra * 64 + ka * 8];
        int rb = wn * 64 + tt * 16 + l15;
        int kb2 = (kk * 4 + quad) ^ (rb & 7);
        bf[tt] = *(bf16x8*)&bs[rb * 64 + kb2 * 8];
      }
#pragma unroll
      for (int mt = 0; mt < 4; ++mt)
#pragma unroll
        for (int nt = 0; nt < 4; ++nt)
          acc[mt][nt] = __builtin_amdgcn_mfma_f32_16x16x32_bf16(
              af[mt], bf[nt], acc[mt][nt], 0, 0, 0);
    }
  }

#pragma unroll
  for (int mt = 0; mt < 4; ++mt)
#pragma unroll
    for (int nt = 0; nt < 4; ++nt)
#pragma unroll
      for (int rr = 0; rr < 4; ++rr) {
        int row = bm * 128 + wm * 64 + mt * 16 + quad * 4 + rr;
        int col = bn * 128 + wn * 64 + nt * 16 + l15;
        float v = acc[mt][nt][rr] + bias[col];
        int n = row >> 11, s = row & 2047, h = col >> 6, d = col & 63;
        if (z == 0) {  // q, pre-scaled into exp2 domain
          qb[(((size_t)(n * H + h) * S) + s) * D + d] = f2bf_rne(v * QSCALE);
        } else {
          kb[(((size_t)(n * H + h) * S) + s) * D + d] = f2bf_rne(v);
        }
      }
}

// ---------------------------------------------------------------------------
// 64x128-tile GEMM core, BK=64, 512 blocks, XCD swizzle: bn=r&7,
// bm=c*8+(r>>3).
// MODE 0: v-projection -> vtb transposed [n,h,d,s] (bf16)
// MODE 1: out projection -> fp32 row-major + bias
// ---------------------------------------------------------------------------
template <int MODE>
__global__ __launch_bounds__(256) void gemm64(const short* __restrict__ A,
                                              const short* __restrict__ Bw,
                                              const float* __restrict__ bias,
                                              void* __restrict__ outp) {
  __shared__ __align__(16) short as[64 * 64];   // 8 KB
  __shared__ __align__(16) short bs[128 * 64];  // 16 KB
  const int tid = threadIdx.x;
  const int lane = tid & 63, w = tid >> 6;
  const int l15 = lane & 15, quad = lane >> 4;
  const int wm = w & 1, wn = w >> 1;

  const int b = blockIdx.x;
  const int c = b & 7, r = b >> 3;
  const int bn = r & 7;
  const int bm = c * 8 + (r >> 3);  // 0..63

  // A: 2 segments per wave (8 KB); B: 4 segments per wave (16 KB).
  const short* agp[2];
  int aldsb[2];
#pragma unroll
  for (int cc = 0; cc < 2; ++cc) {
    int seg = w * 2 + cc;
    int row = seg * 8 + (lane >> 3), kc = lane & 7;
    int l = kc ^ (row & 7);
    aldsb[cc] = seg * 512;
    agp[cc] = &A[(size_t)(bm * 64 + row) * E + l * 8];
  }
  const short* bgp[4];
  int bldsb[4];
#pragma unroll
  for (int cc = 0; cc < 4; ++cc) {
    int seg = w * 4 + cc;
    int row = seg * 8 + (lane >> 3), kc = lane & 7;
    int l = kc ^ (row & 7);
    bldsb[cc] = seg * 512;
    bgp[cc] = &Bw[(size_t)(bn * 128 + row) * E + l * 8];
  }

  f32x4 acc[2][4] = {};
  for (int k0 = 0; k0 < E; k0 += 64) {
    __syncthreads();
#pragma unroll
    for (int cc = 0; cc < 2; ++cc) gl_lds16(agp[cc] + k0, &as[aldsb[cc]]);
#pragma unroll
    for (int cc = 0; cc < 4; ++cc) gl_lds16(bgp[cc] + k0, &bs[bldsb[cc]]);
    __syncthreads();

#pragma unroll
    for (int kk = 0; kk < 2; ++kk) {
      bf16x8 af[2], bf[4];
#pragma unroll
      for (int tt = 0; tt < 2; ++tt) {
        int ra = wm * 32 + tt * 16 + l15;
        int ka = (kk * 4 + quad) ^ (ra & 7);
        af[tt] = *(bf16x8*)&as[ra * 64 + ka * 8];
      }
#pragma unroll
      for (int tt = 0; tt < 4; ++tt) {
        int rb = wn * 64 + tt * 16 + l15;
        int kb2 = (kk * 4 + quad) ^ (rb & 7);
        bf[tt] = *(bf16x8*)&bs[rb * 64 + kb2 * 8];
      }
#pragma unroll
      for (int mt = 0; mt < 2; ++mt)
#pragma unroll
        for (int nt = 0; nt < 4; ++nt)
          acc[mt][nt] = __builtin_amdgcn_mfma_f32_16x16x32_bf16(
              af[mt], bf[nt], acc[mt][nt], 0, 0, 0);
    }
  }

#pragma unroll
  for (int mt = 0; mt < 2; ++mt)
#pragma unroll
    for (int nt = 0; nt < 4; ++nt)
#pragma unroll
      for (int rr = 0; rr < 4; ++rr) {
        int row = bm * 64 + wm * 32 + mt * 16 + quad * 4 + rr;
        int col = bn * 128 + wn * 64 + nt * 16 + l15;
        float v = acc[mt][nt][rr] + bias[col];
        if (MODE == 0) {
          int n = row >> 11, s = row & 2047, h = col >> 6, d = col & 63;
          ((short*)outp)[(((size_t)(n * H + h) * D) + d) * S + s] =
              f2bf_rne(v);
        } else {
          ((float*)outp)[(size_t)row * E + col] = v;
        }
      }
}

// ---------------------------------------------------------------------------
// Flash attention (R15 form, unchanged — measured 40.8 us): 8 waves x 32
// q-rows, grid (8,32), XCD-pinned heads, swapped QK^T on mfma_32x32x16,
// in-register P via cvt_pk+permlane32_swap, dbuf K/V, setprio on MFMA,
// lds_barrier per tile.
// ---------------------------------------------------------------------------
__global__ __launch_bounds__(512) void attn_kernel(const short* __restrict__ q,
                                                   const short* __restrict__ k,
                                                   const short* __restrict__ vt,
                                                   short* __restrict__ ctx) {
  __shared__ __align__(16) short ksb[2][128 * 72];  // 128 keys x 64 d
  __shared__ __align__(16) short vsb[2][64 * 136];  // 64 d x 128 keys (V^T)

  const int tid = threadIdx.x;
  const int lane = tid & 63, wv = tid >> 6;  // 8 waves
  const int l31 = lane & 31, h = lane >> 5;

  const int bid = blockIdx.y * gridDim.x + blockIdx.x;  // 0..255
  const int c = bid & 7, r = bid >> 3;
  const int qt = r & 7;             // 8 q-tiles of 256 rows
  const int hz = c * 4 + (r >> 3);  // 0..31, 4 heads per XCD
  const int hh = hz & 15, nn = hz >> 4;

  const size_t base = (size_t)(nn * H + hh) * S * D;
  const int q0 = qt * 256 + wv * 32;

  bf16x8 qf[4];
#pragma unroll
  for (int kd = 0; kd < 4; ++kd)
    qf[kd] = *(const bf16x8*)&q[base + (size_t)(q0 + l31) * D + kd * 16 + h * 8];

  f32x16 o[2] = {};   // O[q=crow(r,h)][d=dc*32+l31]
  float lsum = 0.f;

  bf16x8 pk[2], pv[2];
  auto loadKV = [&](int j0) {
#pragma unroll
    for (int cc = 0; cc < 2; ++cc) {
      int ch = cc * 512 + tid;
      int kr = ch >> 3, kc = (ch & 7) * 8;   // 128 x 64
      pk[cc] = *(const bf16x8*)&k[base + (size_t)(j0 + kr) * D + kc];
      int vr = ch >> 4, vc = (ch & 15) * 8;  // 64 x 128
      pv[cc] = *(const bf16x8*)&vt[base + (size_t)vr * S + j0 + vc];
    }
  };
  auto storeKV = [&](int bufi) {
#pragma unroll
    for (int cc = 0; cc < 2; ++cc) {
      int ch = cc * 512 + tid;
      int kr = ch >> 3, kc = (ch & 7) * 8;
      *(bf16x8*)&ksb[bufi][kr * 72 + kc] = pk[cc];
      int vr = ch >> 4, vc = (ch & 15) * 8;
      *(bf16x8*)&vsb[bufi][vr * 136 + vc] = pv[cc];
    }
  };

  loadKV(0);
  storeKV(0);
  loadKV(128);
  lds_barrier();  // buf0 visible; tile-1 loads stay in flight

  for (int t = 0; t < 16; ++t) {
    const int cur = t & 1;
    if (t + 1 < 16) storeKV(cur ^ 1);      // tile t+1 (regs from last iter)
    if (t + 2 < 16) loadKV((t + 2) * 128); // prefetch tile t+2
    const short* ks = ksb[cur];
    const short* vs = vsb[cur];

#pragma unroll
    for (int half = 0; half < 2; ++half) {
      // QK^T: sc[c2] over keys half*64 + c2*32 + crow(r,h), q = l31.
      f32x16 sc[2] = {};
      __builtin_amdgcn_s_setprio(1);
#pragma unroll
      for (int c2 = 0; c2 < 2; ++c2)
#pragma unroll
        for (int kd = 0; kd < 4; ++kd) {
          bf16x8 kf = *(bf16x8*)&ks[(half * 64 + c2 * 32 + l31) * 72 +
                                    kd * 16 + h * 8];
          sc[c2] = __builtin_amdgcn_mfma_f32_32x32x16_bf16(kf, qf[kd], sc[c2],
                                                           0, 0, 0);
        }
      __builtin_amdgcn_s_setprio(0);

      // Softmax (fixed-base exp2) + in-register P->bf16 repack.
      bf16x8 pa[4];
#pragma unroll
      for (int c2 = 0; c2 < 2; ++c2) {
        float pe[16];
#pragma unroll
        for (int rr = 0; rr < 16; ++rr) {
          float p = fast_exp2(sc[c2][rr]);
          lsum += p;
          pe[rr] = p;
        }
#pragma unroll
        for (int kk = 0; kk < 2; ++kk) {
          unsigned A0 = cvtpk(pe[8 * kk + 0], pe[8 * kk + 1]);
          unsigned A1 = cvtpk(pe[8 * kk + 2], pe[8 * kk + 3]);
          unsigned B0 = cvtpk(pe[8 * kk + 4], pe[8 * kk + 5]);
          unsigned B1 = cvtpk(pe[8 * kk + 6], pe[8 * kk + 7]);
          plswap(A0, B0);
          plswap(A1, B1);
          u32x4 tt;
          tt[0] = A0; tt[1] = A1; tt[2] = B0; tt[3] = B1;
          pa[c2 * 2 + kk] = __builtin_bit_cast(bf16x8, tt);
        }
      }

      // PV: O[q][d] += P x V. B-frag: V[key=ks2*16+h*8..+7][d=dc*32+l31].
      __builtin_amdgcn_s_setprio(1);
#pragma unroll
      for (int ks2 = 0; ks2 < 4; ++ks2)
#pragma unroll
        for (int dc = 0; dc < 2; ++dc) {
          bf16x8 vf = *(bf16x8*)&vs[(dc * 32 + l31) * 136 + half * 64 +
                                    ks2 * 16 + h * 8];
          o[dc] = __builtin_amdgcn_mfma_f32_32x32x16_bf16(pa[ks2], vf, o[dc],
                                                          0, 0, 0);
        }
      __builtin_amdgcn_s_setprio(0);
    }
    lds_barrier();
  }

  // lane (l31,h) holds partial denom for q=l31 over its h-half keys.
  lsum += __shfl_xor(lsum, 32);
  float invq = 1.0f / lsum;  // denom for q = l31

#pragma unroll
  for (int rr = 0; rr < 16; ++rr) {
    int crow = (rr & 3) + 8 * (rr >> 2) + 4 * h;   // q-row of this reg
    float inv = __shfl(invq, crow);                // lane crow owns that q
    int row = q0 + crow;
#pragma unroll
    for (int dc = 0; dc < 2; ++dc) {
      ctx[((size_t)(nn * S + row)) * E + hh * D + dc * 32 + l31] =
          f2bf_rne(o[dc][rr] * inv);
    }
  }
}

// ---------------------------------------------------------------------------
extern "C" void kernel_launch(void* const* d_in, const int* in_sizes, int n_in,
                              void* d_out, int out_size, void* d_ws,
                              size_t ws_size, hipStream_t stream) {
  const float* values  = (const float*)d_in[0];
  const float* keys    = (const float*)d_in[1];
  const float* queries = (const float*)d_in[2];
  const float* b_v = (const float*)d_in[4];
  const float* b_k = (const float*)d_in[6];
  const float* b_q = (const float*)d_in[8];
  const float* W_v = (const float*)d_in[3];
  const float* W_k = (const float*)d_in[5];
  const float* W_q = (const float*)d_in[7];
  const float* W_o = (const float*)d_in[9];
  const float* b_o = (const float*)d_in[10];

  const size_t X = (size_t)M * E;      // 4M elements (8 MB bf16)
  const size_t W = (size_t)E * E;      // 1M elements (2 MB bf16)

  // d_out (16 MB): qbf [0..X) + qb [X..2X); both dead before gemm64<1>
  // overwrites d_out with fp32.
  short* qbf = (short*)d_out;
  short* qb  = (short*)d_out + X;
  // d_ws (32 MB): kbf (->ctx after qk_gemm), vbf (->kb after gemm64<0>),
  // vtb, 4 bf16 weights.
  short* kbf = (short*)d_ws;           // [0 .. X)
  short* vbf = kbf + X;                // [X .. 2X)
  short* vtb = vbf + X;                // [2X .. 3X)
  short* wqb = vtb + X;                // [3X ..)
  short* wkb = wqb + W;
  short* wvb = wkb + W;
  short* wob = wvb + W;
  short* ctx = kbf;   // kbf dead after qk_gemm
  short* kb  = vbf;   // vbf dead after gemm64<0> (runs BEFORE qk_gemm)

  cast_all<<<dim3(2048, 7), 256, 0, stream>>>(queries, keys, values, W_q, W_k,
                                              W_v, W_o, qbf, kbf, vbf, wqb,
                                              wkb, wvb, wob);
  gemm64<0><<<512, 256, 0, stream>>>(vbf, wvb, b_v, vtb);
  qk_gemm<<<512, 256, 0, stream>>>(qbf, kbf, wqb, wkb, b_q, b_k, qb, kb);
  attn_kernel<<<dim3(8, 32), 512, 0, stream>>>(qb, kb, vtb, ctx);
  gemm64<1><<<512, 256, 0, stream>>>(ctx, wob, b_o, d_out);
}